// Round 1
// baseline (154.484 us; speedup 1.0000x reference)
//
#include <hip/hip_runtime.h>
#include <hip/hip_bf16.h>

#define NB 8
#define SEQ 2048
#define HD 1024
#define DK 64

typedef __attribute__((ext_vector_type(4))) float f32x4;
typedef __attribute__((ext_vector_type(8))) short bf16x8;

__device__ __forceinline__ short f2bf(float f) {
    union { float f; unsigned u; } v; v.f = f;
    unsigned r = v.u + 0x7fffu + ((v.u >> 16) & 1u);
    return (short)(r >> 16);
}

// ---------------- lengths + mask-layout detection ----------------
// padding_mask is monotone per row (tail padding) -> length = #zeros.
// Encoding of the bool array is harness-dependent (int32 / uint8 / f32);
// detect at runtime. Words 0..4095 are in-bounds under every encoding.
__global__ void lengths_kernel(const unsigned* __restrict__ mask, int* __restrict__ lengths) {
    __shared__ int sdet;
    __shared__ int scnt;
    int b = blockIdx.x, t = threadIdx.x;
    if (t == 0) { sdet = 0; scnt = 0; }
    __syncthreads();
    int det = 0;
    for (int i = t; i < 4096; i += 256) {
        unsigned w = mask[i];
        if (w > 1u && w != 0x3F800000u) det = 1;   // not {0,1} and not 1.0f -> byte layout
    }
    if (det) atomicOr(&sdet, 1);
    __syncthreads();
    int cnt = 0;
    if (sdet) {
        const unsigned char* m8 = (const unsigned char*)mask;
        for (int s = t; s < SEQ; s += 256) cnt += (m8[b * SEQ + s] == 0) ? 1 : 0;
    } else {
        // int32 (0/1) or f32 (0.0f/1.0f): zero-word test works for both
        for (int s = t; s < SEQ; s += 256) cnt += (mask[b * SEQ + s] == 0u) ? 1 : 0;
    }
    atomicAdd(&scnt, cnt);
    __syncthreads();
    if (t == 0) lengths[b] = scnt;
}

// ---------------- W transpose + bf16 convert: Wt[3][64][1024] ----------------
__global__ void wt_kernel(const float* __restrict__ Wq, const float* __restrict__ Wk,
                          const float* __restrict__ Wv, short* __restrict__ Wt) {
    int idx = blockIdx.x * 256 + threadIdx.x;   // grid sized exactly 3*64*1024
    int m = idx >> 16, r = (idx >> 10) & 63, k = idx & 1023;
    const float* W = (m == 0) ? Wq : (m == 1) ? Wk : Wv;
    Wt[idx] = f2bf(W[k * DK + r]);
}

// ---------------- QKV projection (register-only MFMA GEMM) ----------------
// Per wave: 16 rows x 64 cols x 3 matrices. A-frags from x (f32->bf16 in reg),
// B-frags from pre-transposed Wt (contiguous 16B/lane, L1/L2-resident).
__global__ __launch_bounds__(256) void qkv_kernel(
    const float* __restrict__ x,
    const float* __restrict__ bq, const float* __restrict__ bk, const float* __restrict__ bv,
    const short* __restrict__ Wt,
    short* __restrict__ Q, short* __restrict__ K, short* __restrict__ Vt) {
    int t = threadIdx.x;
    int w = t >> 6, lane = t & 63;
    int g = lane >> 4, c = lane & 15;
    int rowg0 = blockIdx.x * 64 + w * 16;

    f32x4 zero4 = {0.f, 0.f, 0.f, 0.f};
    f32x4 acc[3][4];
    #pragma unroll
    for (int m = 0; m < 3; m++)
        #pragma unroll
        for (int n = 0; n < 4; n++) acc[m][n] = zero4;

    const float* xr = x + (size_t)(rowg0 + c) * HD;
    for (int k0 = 0; k0 < HD; k0 += 64) {
        bf16x8 a[2];
        #pragma unroll
        for (int kh = 0; kh < 2; kh++) {
            const float* p = xr + k0 + kh * 32 + g * 8;
            f32x4 v0 = *(const f32x4*)p;
            f32x4 v1 = *(const f32x4*)(p + 4);
            union { bf16x8 v; short s[8]; } u;
            #pragma unroll
            for (int i = 0; i < 4; i++) { u.s[i] = f2bf(v0[i]); u.s[4 + i] = f2bf(v1[i]); }
            a[kh] = u.v;
        }
        #pragma unroll
        for (int m = 0; m < 3; m++) {
            const short* wm = Wt + m * 65536 + c * 1024 + k0 + g * 8;
            #pragma unroll
            for (int n = 0; n < 4; n++) {
                #pragma unroll
                for (int kh = 0; kh < 2; kh++) {
                    bf16x8 bfr = *(const bf16x8*)(wm + n * 16 * 1024 + kh * 32);
                    acc[m][n] = __builtin_amdgcn_mfma_f32_16x16x32_bf16(a[kh], bfr, acc[m][n], 0, 0, 0);
                }
            }
        }
    }
    // epilogue: Q scaled by 1/sqrt(DK)=0.125 (exact), V stored transposed
    #pragma unroll
    for (int n = 0; n < 4; n++) {
        int col = n * 16 + c;
        float bqv = bq[col], bkv = bk[col], bvv = bv[col];
        #pragma unroll
        for (int j = 0; j < 4; j++) {
            int rg = rowg0 + 4 * g + j;
            size_t o = (size_t)rg * DK + col;
            Q[o] = f2bf((acc[0][n][j] + bqv) * 0.125f);
            K[o] = f2bf(acc[1][n][j] + bkv);
            int bb = rg >> 11, s = rg & (SEQ - 1);
            Vt[(size_t)bb * DK * SEQ + (size_t)col * SEQ + s] = f2bf(acc[2][n][j] + bvv);
        }
    }
}

// ---------------- flash attention ----------------
// 1 wave/block, 16 query rows/wave, 32-key tiles. fp32 online softmax,
// bf16 MFMA for QK^T and PV. Work-balanced qfrag pairing (2k <-> NQ-1-k).
__global__ __launch_bounds__(64) void attn_kernel(
    const short* __restrict__ Q, const short* __restrict__ K, const short* __restrict__ Vt,
    const int* __restrict__ lengths, float* __restrict__ out) {
    int bid = blockIdx.x;
    int b = bid >> 7, i = bid & 127;
    int qf = (i & 1) ? (127 - (i >> 1)) : (i >> 1);
    int len = lengths[b];
    int qbase = qf * 16;
    int lane = threadIdx.x;
    int g = lane >> 4, c = lane & 15;
    float* outp = out + ((size_t)b * SEQ + qbase) * DK;

    if (qbase >= len) {   // fully padded query rows -> zeros (d_out is poisoned)
        #pragma unroll
        for (int r = 0; r < 16; r++) outp[r * DK + lane] = 0.f;
        return;
    }

    const short* Qb = Q + ((size_t)b * SEQ + qbase) * DK;
    const short* Kb = K + (size_t)b * SEQ * DK;
    const short* Vb = Vt + (size_t)b * DK * SEQ;

    // A-frag: lane supplies Q[row=c][k=(g*8..)+j]
    bf16x8 qa0 = *(const bf16x8*)(Qb + c * DK + g * 8);
    bf16x8 qa1 = *(const bf16x8*)(Qb + c * DK + 32 + g * 8);

    f32x4 zero4 = {0.f, 0.f, 0.f, 0.f};
    float m_r[4], l_r[4];
    f32x4 acc[4];
    #pragma unroll
    for (int j = 0; j < 4; j++) { m_r[j] = -1e30f; l_r[j] = 0.f; }
    #pragma unroll
    for (int n = 0; n < 4; n++) acc[n] = zero4;

    __shared__ short plds[16][40];   // P transpose buffer, rows padded to 80B

    int kend = min(len, qbase + 16);
    for (int kb = 0; kb < kend; kb += 32) {
        // S-frag: D[row=qbase+4g+j][col=key offset c]
        f32x4 sf0 = zero4, sf1 = zero4;
        {
            bf16x8 kf00 = *(const bf16x8*)(Kb + (kb + c) * DK + g * 8);
            bf16x8 kf01 = *(const bf16x8*)(Kb + (kb + c) * DK + 32 + g * 8);
            sf0 = __builtin_amdgcn_mfma_f32_16x16x32_bf16(qa0, kf00, sf0, 0, 0, 0);
            sf0 = __builtin_amdgcn_mfma_f32_16x16x32_bf16(qa1, kf01, sf0, 0, 0, 0);
            bf16x8 kf10 = *(const bf16x8*)(Kb + (kb + 16 + c) * DK + g * 8);
            bf16x8 kf11 = *(const bf16x8*)(Kb + (kb + 16 + c) * DK + 32 + g * 8);
            sf1 = __builtin_amdgcn_mfma_f32_16x16x32_bf16(qa0, kf10, sf1, 0, 0, 0);
            sf1 = __builtin_amdgcn_mfma_f32_16x16x32_bf16(qa1, kf11, sf1, 0, 0, 0);
        }
        // causal + padding mask
        int key0 = kb + c, key1 = kb + 16 + c;
        #pragma unroll
        for (int j = 0; j < 4; j++) {
            int row = qbase + 4 * g + j;
            if (key0 > row || key0 >= len) sf0[j] = -1e30f;
            if (key1 > row || key1 >= len) sf1[j] = -1e30f;
        }
        // row reductions across the 16 lanes holding one row (lanes share g)
        float tm[4], p0[4], p1[4], rs[4], sc[4];
        #pragma unroll
        for (int j = 0; j < 4; j++) tm[j] = fmaxf(sf0[j], sf1[j]);
        #pragma unroll
        for (int d = 1; d < 16; d <<= 1)
            #pragma unroll
            for (int j = 0; j < 4; j++) tm[j] = fmaxf(tm[j], __shfl_xor(tm[j], d));
        #pragma unroll
        for (int j = 0; j < 4; j++) {
            float mn = fmaxf(m_r[j], tm[j]);
            sc[j] = __expf(m_r[j] - mn);
            m_r[j] = mn;
            p0[j] = __expf(sf0[j] - mn);
            p1[j] = __expf(sf1[j] - mn);
            rs[j] = p0[j] + p1[j];
        }
        #pragma unroll
        for (int d = 1; d < 16; d <<= 1)
            #pragma unroll
            for (int j = 0; j < 4; j++) rs[j] += __shfl_xor(rs[j], d);
        #pragma unroll
        for (int j = 0; j < 4; j++) l_r[j] = l_r[j] * sc[j] + rs[j];
        #pragma unroll
        for (int n = 0; n < 4; n++)
            #pragma unroll
            for (int j = 0; j < 4; j++) acc[n][j] *= sc[j];
        // P: D-layout -> LDS -> A-layout (wave-private; 1-wave block so
        // __syncthreads is effectively just the required waitcnt)
        #pragma unroll
        for (int j = 0; j < 4; j++) {
            plds[4 * g + j][c] = f2bf(p0[j]);
            plds[4 * g + j][16 + c] = f2bf(p1[j]);
        }
        __syncthreads();
        bf16x8 pa = *(const bf16x8*)(&plds[c][g * 8]);
        #pragma unroll
        for (int n = 0; n < 4; n++) {
            bf16x8 vf = *(const bf16x8*)(Vb + (n * 16 + c) * SEQ + kb + g * 8);
            acc[n] = __builtin_amdgcn_mfma_f32_16x16x32_bf16(pa, vf, acc[n], 0, 0, 0);
        }
        __syncthreads();   // WAR protection before next tile's P write
    }
    #pragma unroll
    for (int n = 0; n < 4; n++) {
        #pragma unroll
        for (int j = 0; j < 4; j++) {
            int row = 4 * g + j;
            int rg = qbase + row;
            float o = (rg < len) ? acc[n][j] / l_r[j] : 0.f;
            outp[row * DK + n * 16 + c] = o;
        }
    }
}

extern "C" void kernel_launch(void* const* d_in, const int* in_sizes, int n_in,
                              void* d_out, int out_size, void* d_ws, size_t ws_size,
                              hipStream_t stream) {
    const float* x  = (const float*)d_in[0];
    const unsigned* mask = (const unsigned*)d_in[1];
    const float* Wq = (const float*)d_in[2];
    const float* bq = (const float*)d_in[3];
    const float* Wk = (const float*)d_in[4];
    const float* bk = (const float*)d_in[5];
    const float* Wv = (const float*)d_in[6];
    const float* bv = (const float*)d_in[7];
    float* out = (float*)d_out;

    char* ws = (char*)d_ws;
    int*   lengths = (int*)ws;                       // 32 B
    short* Wt = (short*)(ws + 256);                  // 3*64*1024*2 = 384 KiB
    short* Q  = (short*)(ws + 393472);               // 2 MiB
    short* K  = (short*)(ws + 393472 + 2097152);     // 2 MiB
    short* Vt = (short*)(ws + 393472 + 2 * 2097152); // 2 MiB (transposed [b][d][s])

    hipLaunchKernelGGL(lengths_kernel, dim3(NB), dim3(256), 0, stream, mask, lengths);
    hipLaunchKernelGGL(wt_kernel, dim3(768), dim3(256), 0, stream, Wq, Wk, Wv, Wt);
    hipLaunchKernelGGL(qkv_kernel, dim3((NB * SEQ) / 64), dim3(256), 0, stream,
                       x, bq, bk, bv, Wt, Q, K, Vt);
    hipLaunchKernelGGL(attn_kernel, dim3(NB * (SEQ / 16)), dim3(64), 0, stream,
                       Q, K, Vt, lengths, out);
}

// Round 2
// 110.241 us; speedup vs baseline: 1.4013x; 1.4013x over previous
//
#include <hip/hip_runtime.h>
#include <hip/hip_bf16.h>

#define NB 8
#define SEQ 2048
#define HD 1024
#define DK 64

typedef __attribute__((ext_vector_type(4))) float f32x4;
typedef __attribute__((ext_vector_type(8))) short bf16x8;

__device__ __forceinline__ short f2bf(float f) {
    union { float f; unsigned u; } v; v.f = f;
    unsigned r = v.u + 0x7fffu + ((v.u >> 16) & 1u);
    return (short)(r >> 16);
}
__device__ __forceinline__ float bf2f(short s) {
    union { float f; unsigned u; } v; v.u = ((unsigned)(unsigned short)s) << 16;
    return v.f;
}

// ---------------- lengths + mask-layout detection ----------------
__global__ void lengths_kernel(const unsigned* __restrict__ mask, int* __restrict__ lengths) {
    __shared__ int sdet;
    __shared__ int scnt;
    int b = blockIdx.x, t = threadIdx.x;
    if (t == 0) { sdet = 0; scnt = 0; }
    __syncthreads();
    int det = 0;
    for (int i = t; i < 4096; i += 256) {
        unsigned w = mask[i];
        if (w > 1u && w != 0x3F800000u) det = 1;
    }
    if (det) atomicOr(&sdet, 1);
    __syncthreads();
    int cnt = 0;
    if (sdet) {
        const unsigned char* m8 = (const unsigned char*)mask;
        for (int s = t; s < SEQ; s += 256) cnt += (m8[b * SEQ + s] == 0) ? 1 : 0;
    } else {
        for (int s = t; s < SEQ; s += 256) cnt += (mask[b * SEQ + s] == 0u) ? 1 : 0;
    }
    atomicAdd(&scnt, cnt);
    __syncthreads();
    if (t == 0) lengths[b] = scnt;
}

// ---------------- W pack: MFMA B-fragment order ----------------
// Wp[((((m*16+kb)*2+kh)*4+n)*64+lane)*8+j] = W_m[k][col], k=kb*64+kh*32+g*8+j, col=n*16+c
__global__ void pack_kernel(const float* __restrict__ Wq, const float* __restrict__ Wk,
                            const float* __restrict__ Wv, short* __restrict__ Wp) {
    int idx = blockIdx.x * 256 + threadIdx.x;   // grid exactly 3*16*2*4*64*8 = 196608
    int j = idx & 7, lane = (idx >> 3) & 63, n = (idx >> 9) & 3;
    int kh = (idx >> 11) & 1, kb = (idx >> 12) & 15, m = idx >> 16;
    int g = lane >> 4, c = lane & 15;
    int k = kb * 64 + kh * 32 + g * 8 + j, col = n * 16 + c;
    const float* W = (m == 0) ? Wq : (m == 1) ? Wk : Wv;
    Wp[idx] = f2bf(W[(size_t)k * DK + col]);
}

// ---------------- QKV projection: block = 16 rows, 4 waves K-split ----------------
__global__ __launch_bounds__(256, 3) void qkv_kernel(
    const float* __restrict__ x,
    const float* __restrict__ bq, const float* __restrict__ bk, const float* __restrict__ bv,
    const short* __restrict__ Wp,
    short* __restrict__ Q, short* __restrict__ K, short* __restrict__ Vt) {
    __shared__ float red[4][48][64];
    int t = threadIdx.x;
    int w = t >> 6, lane = t & 63;
    int g = lane >> 4, c = lane & 15;
    int r0 = blockIdx.x * 16;

    f32x4 z = {0.f, 0.f, 0.f, 0.f};
    f32x4 acc[3][4];
    #pragma unroll
    for (int m = 0; m < 3; m++)
        #pragma unroll
        for (int n = 0; n < 4; n++) acc[m][n] = z;

    const float* xr = x + (size_t)(r0 + c) * HD + w * 256;
    #pragma unroll
    for (int kb = 0; kb < 4; kb++) {
        bf16x8 a[2];
        #pragma unroll
        for (int kh = 0; kh < 2; kh++) {
            const float* p = xr + kb * 64 + kh * 32 + g * 8;
            f32x4 v0 = *(const f32x4*)p;
            f32x4 v1 = *(const f32x4*)(p + 4);
            union { bf16x8 v; short s[8]; } u;
            #pragma unroll
            for (int i = 0; i < 4; i++) { u.s[i] = f2bf(v0[i]); u.s[4 + i] = f2bf(v1[i]); }
            a[kh] = u.v;
        }
        int kbg = w * 4 + kb;
        #pragma unroll
        for (int m = 0; m < 3; m++) {
            #pragma unroll
            for (int kh = 0; kh < 2; kh++) {
                const short* bp = Wp + (size_t)(((m * 16 + kbg) * 2 + kh) * 4) * 512 + lane * 8;
                #pragma unroll
                for (int n = 0; n < 4; n++) {
                    bf16x8 bfr = *(const bf16x8*)(bp + n * 512);
                    acc[m][n] = __builtin_amdgcn_mfma_f32_16x16x32_bf16(a[kh], bfr, acc[m][n], 0, 0, 0);
                }
            }
        }
    }
    #pragma unroll
    for (int m = 0; m < 3; m++)
        #pragma unroll
        for (int n = 0; n < 4; n++)
            #pragma unroll
            for (int j = 0; j < 4; j++)
                red[w][(m * 4 + n) * 4 + j][lane] = acc[m][n][j];
    __syncthreads();
    for (int oi = t; oi < 3072; oi += 256) {
        int i = oi >> 6, l = oi & 63;
        float s = red[0][i][l] + red[1][i][l] + red[2][i][l] + red[3][i][l];
        int m = i >> 4, n = (i >> 2) & 3, j = i & 3;
        int gg = l >> 4, cc = l & 15;
        int row = r0 + 4 * gg + j, col = n * 16 + cc;
        if (m == 0) Q[(size_t)row * DK + col] = f2bf((s + bq[col]) * 0.125f);
        else if (m == 1) K[(size_t)row * DK + col] = f2bf(s + bk[col]);
        else {
            int bb = row >> 11, si = row & (SEQ - 1);
            Vt[(size_t)bb * DK * SEQ + (size_t)col * SEQ + si] = f2bf(s + bv[col]);
        }
    }
}

// ---------------- flash attention, KV-split partials ----------------
// block = 1 wave, 32 q-rows (2 frags), one 512-key split, <=16 tile iters
__global__ __launch_bounds__(64, 3) void attn_part(
    const short* __restrict__ Q, const short* __restrict__ K_, const short* __restrict__ Vt,
    const int* __restrict__ lengths,
    short* __restrict__ po, float* __restrict__ pm, float* __restrict__ pl) {
    int bid = blockIdx.x;
    int b = bid >> 8, rest = bid & 255;
    int qt = rest >> 2, s = rest & 3;
    int len = lengths[b];
    int qbase = qt * 32;
    if (qbase >= len) return;
    int kend = min(len, qbase + 32);
    int klo = s * 512;
    int khi = min(kend, klo + 512);
    if (klo >= khi) return;

    int lane = threadIdx.x;
    int g = lane >> 4, c = lane & 15;
    const short* Qb = Q + ((size_t)b * SEQ + qbase) * DK;
    const short* Kb = K_ + (size_t)b * SEQ * DK;
    const short* Vb = Vt + (size_t)b * DK * SEQ;

    bf16x8 qa[2][2];
    #pragma unroll
    for (int f = 0; f < 2; f++)
        #pragma unroll
        for (int kh = 0; kh < 2; kh++)
            qa[f][kh] = *(const bf16x8*)(Qb + (f * 16 + c) * DK + kh * 32 + g * 8);

    f32x4 z = {0.f, 0.f, 0.f, 0.f};
    f32x4 acc[2][4];
    float m_r[2][4], l_r[2][4];
    #pragma unroll
    for (int f = 0; f < 2; f++) {
        #pragma unroll
        for (int n = 0; n < 4; n++) acc[f][n] = z;
        #pragma unroll
        for (int j = 0; j < 4; j++) { m_r[f][j] = -1e30f; l_r[f][j] = 0.f; }
    }

    __shared__ short plds[2][16][40];

    bf16x8 kf[2][2];
    #pragma unroll
    for (int kt = 0; kt < 2; kt++)
        #pragma unroll
        for (int kh = 0; kh < 2; kh++)
            kf[kt][kh] = *(const bf16x8*)(Kb + (klo + kt * 16 + c) * DK + kh * 32 + g * 8);

    for (int kb = klo; kb < khi; kb += 32) {
        f32x4 sf[2][2];
        #pragma unroll
        for (int f = 0; f < 2; f++)
            #pragma unroll
            for (int kt = 0; kt < 2; kt++) {
                f32x4 t0 = __builtin_amdgcn_mfma_f32_16x16x32_bf16(qa[f][0], kf[kt][0], z, 0, 0, 0);
                sf[f][kt] = __builtin_amdgcn_mfma_f32_16x16x32_bf16(qa[f][1], kf[kt][1], t0, 0, 0, 0);
            }
        // prefetch next K tile (overlaps with softmax below)
        int kn = kb + 32;
        bf16x8 kfn[2][2];
        if (kn < khi) {
            #pragma unroll
            for (int kt = 0; kt < 2; kt++)
                #pragma unroll
                for (int kh = 0; kh < 2; kh++)
                    kfn[kt][kh] = *(const bf16x8*)(Kb + (kn + kt * 16 + c) * DK + kh * 32 + g * 8);
        }
        // V loads (independent of softmax)
        bf16x8 vf[4];
        #pragma unroll
        for (int n = 0; n < 4; n++)
            vf[n] = *(const bf16x8*)(Vb + (n * 16 + c) * SEQ + kb + g * 8);

        // mask
        int key0 = kb + c, key1 = kb + 16 + c;
        #pragma unroll
        for (int f = 0; f < 2; f++)
            #pragma unroll
            for (int j = 0; j < 4; j++) {
                int row = qbase + f * 16 + 4 * g + j;
                if (key0 > row || key0 >= len) sf[f][0][j] = -1e30f;
                if (key1 > row || key1 >= len) sf[f][1][j] = -1e30f;
            }
        // online softmax (both frags interleaved for ILP)
        float tm[2][4], p0[2][4], p1[2][4], rs[2][4], sc[2][4];
        #pragma unroll
        for (int f = 0; f < 2; f++)
            #pragma unroll
            for (int j = 0; j < 4; j++) tm[f][j] = fmaxf(sf[f][0][j], sf[f][1][j]);
        #pragma unroll
        for (int d = 1; d < 16; d <<= 1)
            #pragma unroll
            for (int f = 0; f < 2; f++)
                #pragma unroll
                for (int j = 0; j < 4; j++) tm[f][j] = fmaxf(tm[f][j], __shfl_xor(tm[f][j], d));
        #pragma unroll
        for (int f = 0; f < 2; f++)
            #pragma unroll
            for (int j = 0; j < 4; j++) {
                float mn = fmaxf(m_r[f][j], tm[f][j]);
                sc[f][j] = __expf(m_r[f][j] - mn);
                m_r[f][j] = mn;
                p0[f][j] = __expf(sf[f][0][j] - mn);
                p1[f][j] = __expf(sf[f][1][j] - mn);
                rs[f][j] = p0[f][j] + p1[f][j];
            }
        #pragma unroll
        for (int d = 1; d < 16; d <<= 1)
            #pragma unroll
            for (int f = 0; f < 2; f++)
                #pragma unroll
                for (int j = 0; j < 4; j++) rs[f][j] += __shfl_xor(rs[f][j], d);
        #pragma unroll
        for (int f = 0; f < 2; f++) {
            #pragma unroll
            for (int j = 0; j < 4; j++) l_r[f][j] = l_r[f][j] * sc[f][j] + rs[f][j];
            #pragma unroll
            for (int n = 0; n < 4; n++)
                #pragma unroll
                for (int j = 0; j < 4; j++) acc[f][n][j] *= sc[f][j];
        }
        // P: D-layout -> LDS -> A-layout
        #pragma unroll
        for (int f = 0; f < 2; f++)
            #pragma unroll
            for (int j = 0; j < 4; j++) {
                plds[f][4 * g + j][c] = f2bf(p0[f][j]);
                plds[f][4 * g + j][16 + c] = f2bf(p1[f][j]);
            }
        __syncthreads();
        bf16x8 pa[2];
        #pragma unroll
        for (int f = 0; f < 2; f++) pa[f] = *(const bf16x8*)(&plds[f][c][g * 8]);
        #pragma unroll
        for (int f = 0; f < 2; f++)
            #pragma unroll
            for (int n = 0; n < 4; n++)
                acc[f][n] = __builtin_amdgcn_mfma_f32_16x16x32_bf16(pa[f], vf[n], acc[f][n], 0, 0, 0);
        __syncthreads();
        if (kn < khi) {
            #pragma unroll
            for (int kt = 0; kt < 2; kt++)
                #pragma unroll
                for (int kh = 0; kh < 2; kh++) kf[kt][kh] = kfn[kt][kh];
        }
    }
    // write partials (unnormalized O in bf16, m/l in f32)
    size_t pbase = (size_t)bid * 32 * 64;
    #pragma unroll
    for (int f = 0; f < 2; f++)
        #pragma unroll
        for (int n = 0; n < 4; n++)
            #pragma unroll
            for (int j = 0; j < 4; j++)
                po[pbase + (f * 16 + 4 * g + j) * 64 + n * 16 + c] = f2bf(acc[f][n][j]);
    if (c == 0) {
        #pragma unroll
        for (int f = 0; f < 2; f++)
            #pragma unroll
            for (int j = 0; j < 4; j++) {
                int row = f * 16 + 4 * g + j;
                pm[bid * 32 + row] = m_r[f][j];
                pl[bid * 32 + row] = l_r[f][j];
            }
    }
}

// ---------------- combine partials ----------------
__global__ __launch_bounds__(256) void attn_combine(
    const short* __restrict__ po, const float* __restrict__ pm, const float* __restrict__ pl,
    const int* __restrict__ lengths, float* __restrict__ out) {
    int blk = blockIdx.x;               // NB*64 q-tiles
    int b = blk >> 6, qt = blk & 63;
    int qbase = qt * 32;
    int len = lengths[b];
    int kend = min(len, qbase + 32);
    int t = threadIdx.x;
    int lane = t & 63, rq = t >> 6;     // 4 row-groups
    int nact = min(4, (kend + 511) >> 9);
    float* ob = out + ((size_t)b * SEQ + qbase) * DK;
    for (int row = rq; row < 32; row += 4) {
        int r = qbase + row;
        float val = 0.f;
        if (r < len) {
            float M = -1e30f;
            for (int s2 = 0; s2 < nact; s2++) M = fmaxf(M, pm[(blk * 4 + s2) * 32 + row]);
            float L = 0.f, a = 0.f;
            for (int s2 = 0; s2 < nact; s2++) {
                int pidx = (blk * 4 + s2) * 32 + row;
                float wgt = __expf(pm[pidx] - M);
                L += wgt * pl[pidx];
                a += wgt * bf2f(po[(size_t)pidx * 64 + lane]);
            }
            val = a / L;
        }
        ob[(size_t)row * DK + lane] = val;
    }
}

extern "C" void kernel_launch(void* const* d_in, const int* in_sizes, int n_in,
                              void* d_out, int out_size, void* d_ws, size_t ws_size,
                              hipStream_t stream) {
    const float* x  = (const float*)d_in[0];
    const unsigned* mask = (const unsigned*)d_in[1];
    const float* Wq = (const float*)d_in[2];
    const float* bq = (const float*)d_in[3];
    const float* Wk = (const float*)d_in[4];
    const float* bk = (const float*)d_in[5];
    const float* Wv = (const float*)d_in[6];
    const float* bv = (const float*)d_in[7];
    float* out = (float*)d_out;

    char* ws = (char*)d_ws;
    int*   lengths = (int*)ws;                          // 256 B
    short* Wp = (short*)(ws + 256);                     // 384 KiB
    short* Q  = (short*)(ws + 393472);                  // 2 MiB
    short* K  = (short*)(ws + 2490624);                 // 2 MiB
    short* Vt = (short*)(ws + 4587776);                 // 2 MiB
    short* po = (short*)(ws + 6684928);                 // 8 MiB  (2048 blk * 32 * 64 bf16)
    float* pm = (float*)(ws + 15073536);                // 256 KiB
    float* pl = (float*)(ws + 15335680);                // 256 KiB -> total ~15.6 MiB

    hipLaunchKernelGGL(lengths_kernel, dim3(NB), dim3(256), 0, stream, mask, lengths);
    hipLaunchKernelGGL(pack_kernel, dim3(768), dim3(256), 0, stream, Wq, Wk, Wv, Wp);
    hipLaunchKernelGGL(qkv_kernel, dim3((NB * SEQ) / 16), dim3(256), 0, stream,
                       x, bq, bk, bv, Wp, Q, K, Vt);
    hipLaunchKernelGGL(attn_part, dim3(NB * 64 * 4), dim3(64), 0, stream,
                       Q, K, Vt, lengths, po, pm, pl);
    hipLaunchKernelGGL(attn_combine, dim3(NB * 64), dim3(256), 0, stream,
                       po, pm, pl, lengths, out);
}